// Round 1
// baseline (1326.113 us; speedup 1.0000x reference)
//
#include <hip/hip_runtime.h>
#include <stdint.h>
#include <stddef.h>

#define DM 1024
#define SEQ 4096
#define NB 4
#define NTOK (NB*SEQ)

typedef __attribute__((ext_vector_type(8))) short s16x8;
typedef __attribute__((ext_vector_type(4))) float f32x4;

__device__ __forceinline__ unsigned short f2bf(float f) {
  unsigned int u = __float_as_uint(f);
  u += 0x7FFFu + ((u >> 16) & 1u);   // round-to-nearest-even
  return (unsigned short)(u >> 16);
}

__device__ __forceinline__ f32x4 mfma16(s16x8 a, s16x8 b, f32x4 c) {
  return __builtin_amdgcn_mfma_f32_16x16x32_bf16(a, b, c, 0, 0, 0);
}

__device__ __forceinline__ void gload16(const void* g, void* l) {
  __builtin_amdgcn_global_load_lds((const __attribute__((address_space(1))) unsigned int*)g,
                                   (__attribute__((address_space(3))) unsigned int*)l, 16, 0, 0);
}

// ---------------- kernel 1: f32 -> bf16 bulk convert ----------------
__global__ void k_conv(const float* __restrict__ s, unsigned short* __restrict__ d, int n8) {
  int i = blockIdx.x * blockDim.x + threadIdx.x;
  int st = gridDim.x * blockDim.x;
  for (; i < n8; i += st) {
    const f32x4* sp = (const f32x4*)s + (size_t)i * 2;
    f32x4 a = sp[0], b = sp[1];
    s16x8 o;
    o[0] = (short)f2bf(a[0]); o[1] = (short)f2bf(a[1]);
    o[2] = (short)f2bf(a[2]); o[3] = (short)f2bf(a[3]);
    o[4] = (short)f2bf(b[0]); o[5] = (short)f2bf(b[1]);
    o[6] = (short)f2bf(b[2]); o[7] = (short)f2bf(b[3]);
    *((s16x8*)d + i) = o;
  }
}

// ---------------- kernel 2: fused QKV projection GEMM ----------------
// C[m,e] = sum_d A[m,d]*W[e,d] + bias[e]   (both operands k-major: B^T GEMM)
// 128x128 tile, BK=64, 4 waves (each 64x64), global_load_lds w/ pre-swizzled src.
__global__ __launch_bounds__(256, 2) void k_qkv(
    const unsigned short* __restrict__ xb, const unsigned short* __restrict__ wb,
    const float* __restrict__ b0, const float* __restrict__ b1, const float* __restrict__ b2,
    unsigned short* __restrict__ qo, unsigned short* __restrict__ ko, unsigned short* __restrict__ vo)
{
  __shared__ unsigned short lds[2][2][128 * 64];   // 64 KB: [buf][A/B][row*64+col]
  const int z = blockIdx.z;
  const unsigned short* W = wb + (size_t)z * DM * DM;
  const float* bias = (z == 0) ? b0 : (z == 1) ? b1 : b2;
  unsigned short* out = (z == 0) ? qo : (z == 1) ? ko : vo;
  const int mbase = blockIdx.y * 128, nbase = blockIdx.x * 128;
  const int tid = threadIdx.x, lane = tid & 63, wid = tid >> 6;
  const int wr = wid >> 1, wc = wid & 1;
  const int l7 = lane & 7, l3 = lane >> 3, l15 = lane & 15, lg = lane >> 4;
  const int scol = ((l7 ^ l3) << 3);   // swizzled source element offset within 64-elem row

  f32x4 acc[4][4];
  #pragma unroll
  for (int m = 0; m < 4; m++)
    #pragma unroll
    for (int n = 0; n < 4; n++) { acc[m][n][0]=0.f; acc[m][n][1]=0.f; acc[m][n][2]=0.f; acc[m][n][3]=0.f; }

  auto stage = [&](int buf, int kt) {
    const int kb_ = kt * 64;
    #pragma unroll
    for (int j = 0; j < 8; j++) {
      int i = wid * 8 + j;
      if (i < 16) {
        const unsigned short* src = xb + (size_t)(mbase + i * 8 + l3) * DM + kb_ + scol;
        gload16(src, &lds[buf][0][i * 512]);
      } else {
        int ib = i - 16;
        const unsigned short* src = W + (size_t)(nbase + ib * 8 + l3) * DM + kb_ + scol;
        gload16(src, &lds[buf][1][ib * 512]);
      }
    }
  };

  auto compute = [&](int buf) {
    s16x8 af[4][2], bf[4][2];
    #pragma unroll
    for (int m = 0; m < 4; m++)
      #pragma unroll
      for (int k2 = 0; k2 < 2; k2++) {
        int row = wr * 64 + m * 16 + l15;
        int off = (row * 128 + k2 * 64 + lg * 16) ^ ((row & 7) << 4);
        af[m][k2] = *(const s16x8*)((const char*)&lds[buf][0][0] + off);
      }
    #pragma unroll
    for (int n = 0; n < 4; n++)
      #pragma unroll
      for (int k2 = 0; k2 < 2; k2++) {
        int row = wc * 64 + n * 16 + l15;
        int off = (row * 128 + k2 * 64 + lg * 16) ^ ((row & 7) << 4);
        bf[n][k2] = *(const s16x8*)((const char*)&lds[buf][1][0] + off);
      }
    #pragma unroll
    for (int k2 = 0; k2 < 2; k2++)
      #pragma unroll
      for (int m = 0; m < 4; m++)
        #pragma unroll
        for (int n = 0; n < 4; n++)
          acc[m][n] = mfma16(af[m][k2], bf[n][k2], acc[m][n]);
  };

  stage(0, 0);
  __syncthreads();
  for (int kt = 0; kt < 16; kt++) {
    int cur = kt & 1;
    if (kt < 15) stage(cur ^ 1, kt + 1);
    compute(cur);
    __syncthreads();
  }

  #pragma unroll
  for (int n = 0; n < 4; n++) {
    int col = nbase + wc * 64 + n * 16 + l15;
    float bb = bias[col];
    #pragma unroll
    for (int m = 0; m < 4; m++) {
      #pragma unroll
      for (int r = 0; r < 4; r++) {
        int row = mbase + wr * 64 + m * 16 + lg * 4 + r;
        out[(size_t)row * DM + col] = f2bf(acc[m][n][r] + bb);
      }
    }
  }
}

// ---------------- kernel 3: V -> V^T transpose (per batch) ----------------
__global__ void k_transpose(const unsigned short* __restrict__ v, unsigned short* __restrict__ vt) {
  __shared__ unsigned short t[64][65];
  const int b = blockIdx.z;
  const int rbase = blockIdx.x * 64;   // token dim
  const int cbase = blockIdx.y * 64;   // channel dim
  const unsigned short* vb = v + (size_t)b * SEQ * DM;
  unsigned short* vtb = vt + (size_t)b * DM * SEQ;
  const int tid = threadIdx.x;
  #pragma unroll
  for (int it = 0; it < 16; it++) {
    int idx = it * 256 + tid;
    int r = idx >> 6, c = idx & 63;
    t[r][c] = vb[(size_t)(rbase + r) * DM + cbase + c];
  }
  __syncthreads();
  #pragma unroll
  for (int it = 0; it < 16; it++) {
    int idx = it * 256 + tid;
    int oc = idx >> 6, ot = idx & 63;   // oc: channel, ot: token
    vtb[(size_t)(cbase + oc) * SEQ + rbase + ot] = t[ot][oc];
  }
}

// ---------------- kernel 4: flash attention ----------------
// BQ=32 q-rows/block, BK=64 keys/tile, 8 waves.
// QK^T: d-split (wave w owns dims [w*128, w*128+128)), partials reduced via LDS.
// PV:   col-split (wave w owns out cols [w*128, w*128+128)).
__global__ __launch_bounds__(512, 2) void k_flash(
    const unsigned short* __restrict__ Q, const unsigned short* __restrict__ K,
    const unsigned short* __restrict__ VT, float* __restrict__ out)
{
  __shared__ float Sp[8][32 * 64];          // 64 KB partial scores
  __shared__ unsigned short P[32][72];      // bf16 probs, padded rows
  __shared__ float mrun[32], lrun[32], ftile[32];
  const int b = blockIdx.y, qbase = blockIdx.x * 32;
  const int tid = threadIdx.x, lane = tid & 63, w = tid >> 6;
  const int l15 = lane & 15, lg = lane >> 4;
  const unsigned short* Qb = Q + (size_t)b * SEQ * DM;
  const unsigned short* Kb = K + (size_t)b * SEQ * DM;
  const unsigned short* VTb = VT + (size_t)b * DM * SEQ;

  if (tid < 32) { mrun[tid] = -1e30f; lrun[tid] = 0.f; }

  // Q fragments for this wave's d-chunk, held in registers for the whole block
  s16x8 qf[2][4];
  #pragma unroll
  for (int rs = 0; rs < 2; rs++)
    #pragma unroll
    for (int ks = 0; ks < 4; ks++)
      qf[rs][ks] = *(const s16x8*)(Qb + (size_t)(qbase + rs * 16 + l15) * DM + w * 128 + ks * 32 + lg * 8);

  f32x4 oacc[2][8];
  #pragma unroll
  for (int rs = 0; rs < 2; rs++)
    #pragma unroll
    for (int c2 = 0; c2 < 8; c2++) { oacc[rs][c2][0]=0.f; oacc[rs][c2][1]=0.f; oacc[rs][c2][2]=0.f; oacc[rs][c2][3]=0.f; }

  __syncthreads();

  const int sr = tid >> 4, sj = tid & 15;   // softmax row / col-group (same data as this thread's reduce)

  for (int kt = 0; kt < SEQ / 64; kt++) {
    const int kbase = kt * 64;

    // ---- QK^T partial over this wave's 128 dims ----
    f32x4 s[2][4];
    #pragma unroll
    for (int rs = 0; rs < 2; rs++)
      #pragma unroll
      for (int cs = 0; cs < 4; cs++) { s[rs][cs][0]=0.f; s[rs][cs][1]=0.f; s[rs][cs][2]=0.f; s[rs][cs][3]=0.f; }
    #pragma unroll
    for (int cs = 0; cs < 4; cs++) {
      #pragma unroll
      for (int ks = 0; ks < 4; ks++) {
        s16x8 kf = *(const s16x8*)(Kb + (size_t)(kbase + cs * 16 + l15) * DM + w * 128 + ks * 32 + lg * 8);
        s[0][cs] = mfma16(qf[0][ks], kf, s[0][cs]);
        s[1][cs] = mfma16(qf[1][ks], kf, s[1][cs]);
      }
    }
    // write partials to LDS
    #pragma unroll
    for (int rs = 0; rs < 2; rs++)
      #pragma unroll
      for (int cs = 0; cs < 4; cs++)
        #pragma unroll
        for (int r = 0; r < 4; r++)
          Sp[w][(rs * 16 + lg * 4 + r) * 64 + cs * 16 + l15] = s[rs][cs][r];
    __syncthreads();

    // ---- reduce partials (this thread's 4 elems == its softmax elems) ----
    f32x4 sv = ((const f32x4*)&Sp[0][0])[tid];
    #pragma unroll
    for (int w2 = 1; w2 < 8; w2++) sv += ((const f32x4*)&Sp[w2][0])[tid];
    sv *= 0.03125f;   // 1/sqrt(1024)

    // ---- online softmax (16 threads per row, wave-local) ----
    float pm = fmaxf(fmaxf(sv[0], sv[1]), fmaxf(sv[2], sv[3]));
    pm = fmaxf(pm, __shfl_xor(pm, 1));
    pm = fmaxf(pm, __shfl_xor(pm, 2));
    pm = fmaxf(pm, __shfl_xor(pm, 4));
    pm = fmaxf(pm, __shfl_xor(pm, 8));
    float mold = mrun[sr];
    float mnew = fmaxf(mold, pm);
    float fsc = __expf(mold - mnew);
    float p0 = __expf(sv[0] - mnew), p1 = __expf(sv[1] - mnew);
    float p2 = __expf(sv[2] - mnew), p3 = __expf(sv[3] - mnew);
    float ps = p0 + p1 + p2 + p3;
    ps += __shfl_xor(ps, 1); ps += __shfl_xor(ps, 2);
    ps += __shfl_xor(ps, 4); ps += __shfl_xor(ps, 8);
    if (sj == 0) { mrun[sr] = mnew; lrun[sr] = lrun[sr] * fsc + ps; ftile[sr] = fsc; }
    unsigned long long pk = (unsigned long long)f2bf(p0)
                          | ((unsigned long long)f2bf(p1) << 16)
                          | ((unsigned long long)f2bf(p2) << 32)
                          | ((unsigned long long)f2bf(p3) << 48);
    *(unsigned long long*)&P[sr][sj * 4] = pk;
    __syncthreads();

    // ---- rescale O accumulators ----
    #pragma unroll
    for (int rs = 0; rs < 2; rs++) {
      float f0 = ftile[rs * 16 + lg * 4 + 0];
      float f1 = ftile[rs * 16 + lg * 4 + 1];
      float f2_ = ftile[rs * 16 + lg * 4 + 2];
      float f3 = ftile[rs * 16 + lg * 4 + 3];
      #pragma unroll
      for (int c2 = 0; c2 < 8; c2++) {
        oacc[rs][c2][0] *= f0; oacc[rs][c2][1] *= f1;
        oacc[rs][c2][2] *= f2_; oacc[rs][c2][3] *= f3;
      }
    }

    // ---- PV: wave's 128 output cols ----
    s16x8 pf[2][2];
    #pragma unroll
    for (int rs = 0; rs < 2; rs++)
      #pragma unroll
      for (int ks = 0; ks < 2; ks++)
        pf[rs][ks] = *(const s16x8*)((const char*)&P[0][0] + (rs * 16 + l15) * 144 + ks * 64 + lg * 16);
    #pragma unroll
    for (int c2 = 0; c2 < 8; c2++) {
      #pragma unroll
      for (int ks = 0; ks < 2; ks++) {
        s16x8 vf = *(const s16x8*)(VTb + (size_t)(w * 128 + c2 * 16 + l15) * SEQ + kbase + ks * 32 + lg * 8);
        oacc[0][c2] = mfma16(pf[0][ks], vf, oacc[0][c2]);
        oacc[1][c2] = mfma16(pf[1][ks], vf, oacc[1][c2]);
      }
    }
  }

  // ---- epilogue: divide by l, store f32 ----
  #pragma unroll
  for (int rs = 0; rs < 2; rs++) {
    float li[4];
    #pragma unroll
    for (int r = 0; r < 4; r++) li[r] = 1.f / lrun[rs * 16 + lg * 4 + r];
    #pragma unroll
    for (int c2 = 0; c2 < 8; c2++) {
      int col = w * 128 + c2 * 16 + l15;
      #pragma unroll
      for (int r = 0; r < 4; r++) {
        int row = qbase + rs * 16 + lg * 4 + r;
        out[((size_t)b * SEQ + row) * DM + col] = oacc[rs][c2][r] * li[r];
      }
    }
  }
}

extern "C" void kernel_launch(void* const* d_in, const int* in_sizes, int n_in,
                              void* d_out, int out_size, void* d_ws, size_t ws_size,
                              hipStream_t stream) {
  const float* x  = (const float*)d_in[0];
  const float* Wq = (const float*)d_in[1];
  const float* bq = (const float*)d_in[2];
  const float* Wk = (const float*)d_in[3];
  const float* bk = (const float*)d_in[4];
  const float* Wv = (const float*)d_in[5];
  const float* bv = (const float*)d_in[6];
  float* out = (float*)d_out;
  char* ws = (char*)d_ws;

  // ws layout (bytes)
  unsigned short* xb = (unsigned short*)(ws);                         // 33,554,432
  unsigned short* wb = (unsigned short*)(ws + 33554432);              //  6,291,456
  unsigned short* qb = (unsigned short*)(ws + 39845888);              // 33,554,432
  unsigned short* kb = (unsigned short*)(ws + 73400320);              // 33,554,432
  unsigned short* vb = (unsigned short*)(ws + 106954752);             // 33,554,432
  unsigned short* vt = (unsigned short*)(ws + 140509184);             // 33,554,432  (total ~166 MB)

  k_conv<<<4096, 256, 0, stream>>>(x, xb, NTOK * DM / 8);
  k_conv<<<512, 256, 0, stream>>>(Wq, wb, DM * DM / 8);
  k_conv<<<512, 256, 0, stream>>>(Wk, wb + DM * DM, DM * DM / 8);
  k_conv<<<512, 256, 0, stream>>>(Wv, wb + 2 * DM * DM, DM * DM / 8);

  k_qkv<<<dim3(8, 128, 3), 256, 0, stream>>>(xb, wb, bq, bk, bv, qb, kb, vb);
  k_transpose<<<dim3(64, 16, 4), 256, 0, stream>>>(vb, vt);
  k_flash<<<dim3(SEQ / 32, NB), 512, 0, stream>>>(qb, kb, vt, out);
}

// Round 2
// 537.303 us; speedup vs baseline: 2.4681x; 2.4681x over previous
//
#include <hip/hip_runtime.h>
#include <stdint.h>
#include <stddef.h>

#define DM 1024
#define SEQ 4096
#define NB 4
#define NTOK (NB*SEQ)

typedef __attribute__((ext_vector_type(8))) short s16x8;
typedef __attribute__((ext_vector_type(4))) float f32x4;

__device__ __forceinline__ unsigned short f2bf(float f) {
  unsigned int u = __float_as_uint(f);
  u += 0x7FFFu + ((u >> 16) & 1u);   // round-to-nearest-even
  return (unsigned short)(u >> 16);
}

__device__ __forceinline__ f32x4 mfma16(s16x8 a, s16x8 b, f32x4 c) {
  return __builtin_amdgcn_mfma_f32_16x16x32_bf16(a, b, c, 0, 0, 0);
}

__device__ __forceinline__ void gload16(const void* g, void* l) {
  __builtin_amdgcn_global_load_lds((const __attribute__((address_space(1))) unsigned int*)g,
                                   (__attribute__((address_space(3))) unsigned int*)l, 16, 0, 0);
}

// ---------------- kernel 1: f32 -> bf16 bulk convert ----------------
__global__ void k_conv(const float* __restrict__ s, unsigned short* __restrict__ d, int n8) {
  int i = blockIdx.x * blockDim.x + threadIdx.x;
  int st = gridDim.x * blockDim.x;
  for (; i < n8; i += st) {
    const f32x4* sp = (const f32x4*)s + (size_t)i * 2;
    f32x4 a = sp[0], b = sp[1];
    s16x8 o;
    o[0] = (short)f2bf(a[0]); o[1] = (short)f2bf(a[1]);
    o[2] = (short)f2bf(a[2]); o[3] = (short)f2bf(a[3]);
    o[4] = (short)f2bf(b[0]); o[5] = (short)f2bf(b[1]);
    o[6] = (short)f2bf(b[2]); o[7] = (short)f2bf(b[3]);
    *((s16x8*)d + i) = o;
  }
}

// ---------------- shared GEMM core: C = A @ B^T (both k-major) ----------------
// 128x128 tile, BK=64, 4 waves (64x64 each), global_load_lds w/ pre-swizzled src.
// EPI: 0 = bf16 out + bias; 1 = fp16 out * scale; 2 = f32 out.
template<int KDIM, int EPI>
__device__ __forceinline__ void gemm_core(
    const unsigned short* __restrict__ A, const unsigned short* __restrict__ B,
    void* __restrict__ outp, int ldc, const float* __restrict__ bias, float scale,
    int mbase, int nbase)
{
  __shared__ unsigned short lds[2][2][128 * 64];   // 64 KB
  const int tid = threadIdx.x, lane = tid & 63, wid = tid >> 6;
  const int wr = wid >> 1, wc = wid & 1;
  const int l7 = lane & 7, l3 = lane >> 3, l15 = lane & 15, lg = lane >> 4;
  const int scol = ((l7 ^ l3) << 3);   // swizzled source element offset within 64-elem row

  f32x4 acc[4][4];
  #pragma unroll
  for (int m = 0; m < 4; m++)
    #pragma unroll
    for (int n = 0; n < 4; n++) { acc[m][n][0]=0.f; acc[m][n][1]=0.f; acc[m][n][2]=0.f; acc[m][n][3]=0.f; }

  auto stage = [&](int buf, int kt) {
    const int kb_ = kt * 64;
    #pragma unroll
    for (int j = 0; j < 8; j++) {
      int i = wid * 8 + j;
      if (i < 16) {
        const unsigned short* src = A + (size_t)(mbase + i * 8 + l3) * KDIM + kb_ + scol;
        gload16(src, &lds[buf][0][i * 512]);
      } else {
        int ib = i - 16;
        const unsigned short* src = B + (size_t)(nbase + ib * 8 + l3) * KDIM + kb_ + scol;
        gload16(src, &lds[buf][1][ib * 512]);
      }
    }
  };

  auto compute = [&](int buf) {
    s16x8 af[4][2], bf[4][2];
    #pragma unroll
    for (int m = 0; m < 4; m++)
      #pragma unroll
      for (int k2 = 0; k2 < 2; k2++) {
        int row = wr * 64 + m * 16 + l15;
        int off = (row * 128 + k2 * 64 + lg * 16) ^ ((row & 7) << 4);
        af[m][k2] = *(const s16x8*)((const char*)&lds[buf][0][0] + off);
      }
    #pragma unroll
    for (int n = 0; n < 4; n++)
      #pragma unroll
      for (int k2 = 0; k2 < 2; k2++) {
        int row = wc * 64 + n * 16 + l15;
        int off = (row * 128 + k2 * 64 + lg * 16) ^ ((row & 7) << 4);
        bf[n][k2] = *(const s16x8*)((const char*)&lds[buf][1][0] + off);
      }
    #pragma unroll
    for (int k2 = 0; k2 < 2; k2++)
      #pragma unroll
      for (int m = 0; m < 4; m++)
        #pragma unroll
        for (int n = 0; n < 4; n++)
          acc[m][n] = mfma16(af[m][k2], bf[n][k2], acc[m][n]);
  };

  stage(0, 0);
  __syncthreads();
  constexpr int NT = KDIM / 64;
  for (int kt = 0; kt < NT; kt++) {
    int cur = kt & 1;
    if (kt < NT - 1) stage(cur ^ 1, kt + 1);
    compute(cur);
    __syncthreads();
  }

  #pragma unroll
  for (int n = 0; n < 4; n++) {
    int col = nbase + wc * 64 + n * 16 + l15;
    float bb = (EPI == 0) ? bias[col] : 0.f;
    #pragma unroll
    for (int m = 0; m < 4; m++) {
      #pragma unroll
      for (int r = 0; r < 4; r++) {
        int row = mbase + wr * 64 + m * 16 + lg * 4 + r;
        float v = acc[m][n][r];
        if (EPI == 0) {
          ((unsigned short*)outp)[(size_t)row * ldc + col] = f2bf(v + bb);
        } else if (EPI == 1) {
          _Float16 h = (_Float16)(v * scale);
          ((unsigned short*)outp)[(size_t)row * ldc + col] = __builtin_bit_cast(unsigned short, h);
        } else {
          ((float*)outp)[(size_t)row * ldc + col] = v;
        }
      }
    }
  }
}

// ---------------- kernel 2: fused QKV projection ----------------
__global__ __launch_bounds__(256, 2) void k_qkv(
    const unsigned short* __restrict__ xb, const unsigned short* __restrict__ wb,
    const float* __restrict__ b0, const float* __restrict__ b1, const float* __restrict__ b2,
    unsigned short* __restrict__ qo, unsigned short* __restrict__ ko, unsigned short* __restrict__ vo)
{
  const int z = blockIdx.z;
  gemm_core<DM, 0>(xb, wb + (size_t)z * DM * DM,
                   (z == 0) ? qo : (z == 1) ? ko : vo, DM,
                   (z == 0) ? b0 : (z == 1) ? b1 : b2, 0.f,
                   blockIdx.y * 128, blockIdx.x * 128);
}

// ---------------- kernel 3: V -> V^T transpose (per batch) ----------------
__global__ void k_transpose(const unsigned short* __restrict__ v, unsigned short* __restrict__ vt) {
  __shared__ unsigned short t[64][65];
  const int b = blockIdx.z;
  const int rbase = blockIdx.x * 64;   // token dim
  const int cbase = blockIdx.y * 64;   // channel dim
  const unsigned short* vb = v + (size_t)b * SEQ * DM;
  unsigned short* vtb = vt + (size_t)b * DM * SEQ;
  const int tid = threadIdx.x;
  #pragma unroll
  for (int it = 0; it < 16; it++) {
    int idx = it * 256 + tid;
    int r = idx >> 6, c = idx & 63;
    t[r][c] = vb[(size_t)(rbase + r) * DM + cbase + c];
  }
  __syncthreads();
  #pragma unroll
  for (int it = 0; it < 16; it++) {
    int idx = it * 256 + tid;
    int oc = idx >> 6, ot = idx & 63;
    vtb[(size_t)(cbase + oc) * SEQ + rbase + ot] = t[ot][oc];
  }
}

// ---------------- kernel 4: scores GEMM  S = Q @ K^T * scale -> fp16 ----------------
__global__ __launch_bounds__(256, 2) void k_sgemm(
    const unsigned short* __restrict__ qb, const unsigned short* __restrict__ kb,
    unsigned short* __restrict__ sc0, unsigned short* __restrict__ sc1, int bb)
{
  const int z = blockIdx.z;
  gemm_core<DM, 1>(qb + (size_t)(bb + z) * SEQ * DM, kb + (size_t)(bb + z) * SEQ * DM,
                   z ? sc1 : sc0, SEQ, nullptr, 0.03125f,
                   blockIdx.y * 128, blockIdx.x * 128);
}

// ---------------- kernel 5: row softmax, in-place fp16 -> normalized bf16 ----------------
__global__ __launch_bounds__(256) void k_softmax(unsigned short* __restrict__ sc0,
                                                 unsigned short* __restrict__ sc1) {
  unsigned short* sc = blockIdx.z ? sc1 : sc0;
  const int row = blockIdx.x * 4 + (threadIdx.x >> 6);
  const int lane = threadIdx.x & 63;
  unsigned short* rp = sc + (size_t)row * SEQ + lane * 8;

  s16x8 v[8];
  #pragma unroll
  for (int j = 0; j < 8; j++) v[j] = *(const s16x8*)(rp + (size_t)j * 512);

  float f[64];
  float m = -1e30f;
  #pragma unroll
  for (int j = 0; j < 8; j++)
    #pragma unroll
    for (int t = 0; t < 8; t++) {
      float x = (float)__builtin_bit_cast(_Float16, (unsigned short)v[j][t]);
      f[j * 8 + t] = x;
      m = fmaxf(m, x);
    }
  m = fmaxf(m, __shfl_xor(m, 1));  m = fmaxf(m, __shfl_xor(m, 2));
  m = fmaxf(m, __shfl_xor(m, 4));  m = fmaxf(m, __shfl_xor(m, 8));
  m = fmaxf(m, __shfl_xor(m, 16)); m = fmaxf(m, __shfl_xor(m, 32));

  float s = 0.f;
  #pragma unroll
  for (int i = 0; i < 64; i++) { f[i] = __expf(f[i] - m); s += f[i]; }
  s += __shfl_xor(s, 1);  s += __shfl_xor(s, 2);  s += __shfl_xor(s, 4);
  s += __shfl_xor(s, 8);  s += __shfl_xor(s, 16); s += __shfl_xor(s, 32);
  float inv = 1.f / s;

  #pragma unroll
  for (int j = 0; j < 8; j++) {
    s16x8 o;
    #pragma unroll
    for (int t = 0; t < 8; t++) o[t] = (short)f2bf(f[j * 8 + t] * inv);
    *(s16x8*)(rp + (size_t)j * 512) = o;
  }
}

// ---------------- kernel 6: O = P @ V  (B-operand = V^T, k-major) ----------------
__global__ __launch_bounds__(256, 2) void k_pv(
    const unsigned short* __restrict__ sc0, const unsigned short* __restrict__ sc1,
    const unsigned short* __restrict__ vt, float* __restrict__ out, int bb)
{
  const int z = blockIdx.z;
  gemm_core<SEQ, 2>(z ? sc1 : sc0, vt + (size_t)(bb + z) * DM * SEQ,
                    out + (size_t)(bb + z) * SEQ * DM, DM, nullptr, 1.f,
                    blockIdx.y * 128, blockIdx.x * 128);
}

extern "C" void kernel_launch(void* const* d_in, const int* in_sizes, int n_in,
                              void* d_out, int out_size, void* d_ws, size_t ws_size,
                              hipStream_t stream) {
  const float* x  = (const float*)d_in[0];
  const float* Wq = (const float*)d_in[1];
  const float* bq = (const float*)d_in[2];
  const float* Wk = (const float*)d_in[3];
  const float* bk = (const float*)d_in[4];
  const float* Wv = (const float*)d_in[5];
  const float* bv = (const float*)d_in[6];
  float* out = (float*)d_out;
  char* ws = (char*)d_ws;

  // ws layout (bytes) — total 166 MB (same proven footprint as round 0)
  unsigned short* xb = (unsigned short*)(ws);                         // 32 MB; reused as sc0 after qkv
  unsigned short* wb = (unsigned short*)(ws + 33554432);              //  6 MB
  unsigned short* qb = (unsigned short*)(ws + 39845888);              // 32 MB
  unsigned short* kb = (unsigned short*)(ws + 73400320);              // 32 MB
  unsigned short* vb = (unsigned short*)(ws + 106954752);             // 32 MB; reused as sc1 after transpose
  unsigned short* vt = (unsigned short*)(ws + 140509184);             // 32 MB
  unsigned short* sc0 = xb;   // dead after k_qkv
  unsigned short* sc1 = vb;   // dead after k_transpose

  k_conv<<<4096, 256, 0, stream>>>(x, xb, NTOK * DM / 8);
  k_conv<<<512, 256, 0, stream>>>(Wq, wb, DM * DM / 8);
  k_conv<<<512, 256, 0, stream>>>(Wk, wb + DM * DM, DM * DM / 8);
  k_conv<<<512, 256, 0, stream>>>(Wv, wb + 2 * DM * DM, DM * DM / 8);

  k_qkv<<<dim3(8, 128, 3), 256, 0, stream>>>(xb, wb, bq, bk, bv, qb, kb, vb);
  k_transpose<<<dim3(64, 16, 4), 256, 0, stream>>>(vb, vt);

  for (int bb = 0; bb < NB; bb += 2) {
    k_sgemm<<<dim3(32, 32, 2), 256, 0, stream>>>(qb, kb, sc0, sc1, bb);
    k_softmax<<<dim3(1024, 1, 2), 256, 0, stream>>>(sc0, sc1);
    k_pv<<<dim3(8, 32, 2), 256, 0, stream>>>(sc0, sc1, vt, out, bb);
  }
}